// Round 5
// baseline (264.669 us; speedup 1.0000x reference)
//
#include <hip/hip_runtime.h>
#include <math.h>

#define N_TOK 4096
#define DM 512

typedef _Float16 f16x8 __attribute__((ext_vector_type(8)));
typedef _Float16 f16x4 __attribute__((ext_vector_type(4)));
typedef float f32x4 __attribute__((ext_vector_type(4)));

__device__ __forceinline__ void async_ld16(const ushort* g, ushort* l) {
  __builtin_amdgcn_global_load_lds(
      (const __attribute__((address_space(1))) void*)g,
      (__attribute__((address_space(3))) void*)l, 16, 0, 0);
}

// ---------------------------------------------------------------------------
// Fused pack + sigma + denom-zero.
// b in [0,2048): pack x (1024 elems = rows 2b,2b+1) + sigma for those rows
// b in [2048,2816): pack Wq|Wk|Wv into concatenated Wc16
// b == 2816: zero denom[4096]
// ---------------------------------------------------------------------------
__global__ __launch_bounds__(256) void pack_sigma(
    const float* __restrict__ x, const float* __restrict__ Wq,
    const float* __restrict__ Wk, const float* __restrict__ Wv,
    const float* __restrict__ Ws, _Float16* __restrict__ x16,
    _Float16* __restrict__ Wc16, float* __restrict__ sg,
    float* __restrict__ denom) {
  const int b = blockIdx.x;
  const int t = threadIdx.x;
  if (b < 2048) {
    int i = b * 1024 + t * 4;
    float4 v = *(const float4*)&x[i];
    f16x4 o;
    o.x = (_Float16)v.x; o.y = (_Float16)v.y;
    o.z = (_Float16)v.z; o.w = (_Float16)v.w;
    *(f16x4*)&x16[i] = o;
    // sigma: threads [0,128) -> row 2b, [128,256) -> row 2b+1
    int col = (t * 4) & 511;
    float4 w = *(const float4*)&Ws[col];
    float p = v.x * w.x + v.y * w.y + v.z * w.z + v.w * w.w;
    __shared__ float red[256];
    red[t] = p;
    __syncthreads();
    int lt = t & 127;
    for (int off = 64; off > 0; off >>= 1) {
      if (lt < off) red[t] += red[t + off];
      __syncthreads();
    }
    if (lt == 0) {
      float s = red[t];
      sg[2 * b + (t >> 7)] = fminf(fmaxf(s, 0.001f), 1.0f);
    }
  } else if (b < 2816) {
    int e = (b - 2048) * 1024 + t * 4;
    const float* src;
    int le = e & (DM * DM - 1);
    if (e < DM * DM) src = Wq + le;
    else if (e < 2 * DM * DM) src = Wk + le;
    else src = Wv + le;
    float4 v = *(const float4*)src;
    f16x4 o;
    o.x = (_Float16)v.x; o.y = (_Float16)v.y;
    o.z = (_Float16)v.z; o.w = (_Float16)v.w;
    *(f16x4*)&Wc16[e] = o;
  } else {
    float4 zz = {0.f, 0.f, 0.f, 0.f};
#pragma unroll
    for (int k = 0; k < 4; ++k) *(float4*)&denom[(t * 4 + k * 1024)] = zz;
  }
}

// ---------------------------------------------------------------------------
// fp16 MFMA NT GEMM: acc[m,n] = sum_k A[m,k]*B[n,k]
// BM=BN=128, BK=32, 256 thr = 4 waves (2x2 of 64x64), 16x16x32 f16 MFMA.
// EPI=1: QKV fused (N=1536): region bn>>9 -> D0(Q16)/D1(K16)/D2(V16), fp16
// EPI=4: E16 = exp(acc*scale) -> D0 fp16 (ldc), row-sums atomicAdd -> denom
// EPI=2: S@V split-K, scaled by 1/denom[row]: z=0 -> Cf fp32; z>0 -> Part16
// ---------------------------------------------------------------------------
template <int EPI>
__global__ __launch_bounds__(256) void mfma_f16(
    const _Float16* __restrict__ A, int lda, const _Float16* __restrict__ B,
    int ldb, int K, float scale, float* __restrict__ Cf, int ldc,
    _Float16* __restrict__ D0, _Float16* __restrict__ D1,
    _Float16* __restrict__ D2, _Float16* __restrict__ Part16,
    float* __restrict__ denom) {
  __shared__ _Float16 lds[2 * 128 * 32];
  __shared__ float dinv[128];
  _Float16* Ah = lds;
  _Float16* Bh = lds + 128 * 32;

  const int t = threadIdx.x;
  const int w = t >> 6, L = t & 63;
  const int wm = (w >> 1) * 64, wn = (w & 1) * 64;
  const int row = L & 15, quad = L >> 4;
  const int bm = blockIdx.y * 128, bn = blockIdx.x * 128;
  const int kbase = blockIdx.z * K;

  if (EPI == 2 && t < 128) dinv[t] = 1.0f / denom[bm + t];

  f32x4 acc[4][4] = {{}};

  const int c0 = t, c1 = t + 256;
  const int r0 = c0 >> 2, o0 = (c0 & 3) * 8;
  const int r1 = r0 + 64;

  const ushort* ga0 = (const ushort*)(A + (size_t)(bm + r0) * lda + kbase + o0);
  const ushort* ga1 = (const ushort*)(A + (size_t)(bm + r1) * lda + kbase + o0);
  const ushort* gb0 = (const ushort*)(B + (size_t)(bn + r0) * ldb + kbase + o0);
  const ushort* gb1 = (const ushort*)(B + (size_t)(bn + r1) * ldb + kbase + o0);

  for (int k0 = 0; k0 < K; k0 += 32) {
    async_ld16(ga0, (ushort*)(Ah + c0 * 8));
    async_ld16(ga1, (ushort*)(Ah + c1 * 8));
    async_ld16(gb0, (ushort*)(Bh + c0 * 8));
    async_ld16(gb1, (ushort*)(Bh + c1 * 8));
    ga0 += 32; ga1 += 32; gb0 += 32; gb1 += 32;
    __syncthreads();

    f16x8 a0[4], b0[4];
#pragma unroll
    for (int i = 0; i < 4; ++i)
      a0[i] = *(const f16x8*)&Ah[(wm + i * 16 + row) * 32 + quad * 8];
#pragma unroll
    for (int j = 0; j < 4; ++j)
      b0[j] = *(const f16x8*)&Bh[(wn + j * 16 + row) * 32 + quad * 8];
#pragma unroll
    for (int i = 0; i < 4; ++i)
#pragma unroll
      for (int j = 0; j < 4; ++j)
        acc[i][j] = __builtin_amdgcn_mfma_f32_16x16x32_f16(a0[i], b0[j],
                                                           acc[i][j], 0, 0, 0);
    __syncthreads();
  }

  // epilogue: C/D layout col = lane&15, row = quad*4 + reg
  if (EPI == 1) {
    const int region = bn >> 9;  // uniform per block
    _Float16* D = (region == 0) ? D0 : ((region == 1) ? D1 : D2);
#pragma unroll
    for (int i = 0; i < 4; ++i)
#pragma unroll
      for (int j = 0; j < 4; ++j)
#pragma unroll
        for (int r = 0; r < 4; ++r) {
          int gr = bm + wm + i * 16 + quad * 4 + r;
          int nn = (bn & 511) + wn + j * 16 + row;
          D[(size_t)gr * 512 + nn] = (_Float16)acc[i][j][r];
        }
  } else if (EPI == 4) {
#pragma unroll
    for (int i = 0; i < 4; ++i)
#pragma unroll
      for (int r = 0; r < 4; ++r) {
        int gr = bm + wm + i * 16 + quad * 4 + r;
        float s = 0.f;
#pragma unroll
        for (int j = 0; j < 4; ++j) {
          float e = __expf(acc[i][j][r] * scale);
          int gc = bn + wn + j * 16 + row;
          D0[(size_t)gr * ldc + gc] = (_Float16)e;
          s += e;
        }
        s += __shfl_xor(s, 1);
        s += __shfl_xor(s, 2);
        s += __shfl_xor(s, 4);
        s += __shfl_xor(s, 8);
        if (row == 0) atomicAdd(&denom[gr], s);
      }
  } else {  // EPI == 2
    const int z = blockIdx.z;
#pragma unroll
    for (int i = 0; i < 4; ++i)
#pragma unroll
      for (int j = 0; j < 4; ++j)
#pragma unroll
        for (int r = 0; r < 4; ++r) {
          int lr = wm + i * 16 + quad * 4 + r;
          int gr = bm + lr;
          int gc = bn + wn + j * 16 + row;
          float v = acc[i][j][r] * dinv[lr];
          if (z == 0)
            Cf[(size_t)gr * ldc + gc] = v;
          else
            Part16[(size_t)(z - 1) * 2097152 + (size_t)gr * ldc + gc] =
                (_Float16)v;
        }
  }
}

// ---------------------------------------------------------------------------
// V16 [4096x512] fp16 -> VT16 [512][4096] fp16
// ---------------------------------------------------------------------------
__global__ __launch_bounds__(256) void transpose16(
    const _Float16* __restrict__ V16, _Float16* __restrict__ VT) {
  __shared__ _Float16 T[32][34];
  const int t = threadIdx.x;
  const int r = t >> 3, c4 = (t & 7) * 4;
  f16x4 v = *(const f16x4*)&V16[(size_t)(blockIdx.y * 32 + r) * 512 +
                                blockIdx.x * 32 + c4];
  T[r][c4] = v.x; T[r][c4 + 1] = v.y; T[r][c4 + 2] = v.z; T[r][c4 + 3] = v.w;
  __syncthreads();
  f16x4 o;
  o.x = T[c4][r]; o.y = T[c4 + 1][r]; o.z = T[c4 + 2][r]; o.w = T[c4 + 3][r];
  *(f16x4*)&VT[(size_t)(blockIdx.x * 32 + r) * 4096 + blockIdx.y * 32 + c4] = o;
}

// ---------------------------------------------------------------------------
// Fused tail:
//  b in [0,4096)            : P rows (Gaussian prior)
//  b in [4096,6144)         : Z += fp16 partials
//  b in [6144,6144+16384)   : S = E16 * (1/denom[row])   (softmax normalize)
// ---------------------------------------------------------------------------
__global__ __launch_bounds__(256) void tail_kernel(
    const float* __restrict__ sigma, float* __restrict__ P,
    float* __restrict__ Z, const _Float16* __restrict__ Part16,
    const _Float16* __restrict__ E16, const float* __restrict__ denom,
    float* __restrict__ S) {
  const int t = threadIdx.x;
  const int b = blockIdx.x;
  if (b >= 6144) {
    int idx = (b - 6144) * 1024 + t * 4;
    int rw = (b - 6144) >> 2;  // 4 blocks per row of 4096
    float inv = 1.0f / denom[rw];
    f16x4 e = *(const f16x4*)&E16[idx];
    float4 o;
    o.x = (float)e.x * inv; o.y = (float)e.y * inv;
    o.z = (float)e.z * inv; o.w = (float)e.w * inv;
    *(float4*)&S[idx] = o;
    return;
  }
  if (b >= 4096) {
    int i = (b - 4096) * 1024 + t * 4;
    float4 z = *(const float4*)&Z[i];
    f16x4 a = *(const f16x4*)&Part16[i];
    f16x4 c = *(const f16x4*)&Part16[2097152 + i];
    f16x4 d = *(const f16x4*)&Part16[2 * 2097152 + i];
    z.x += (float)a.x + (float)c.x + (float)d.x;
    z.y += (float)a.y + (float)c.y + (float)d.y;
    z.z += (float)a.z + (float)c.z + (float)d.z;
    z.w += (float)a.w + (float)c.w + (float)d.w;
    *(float4*)&Z[i] = z;
    return;
  }
  __shared__ float red[256];
  const int i = b;
  const float sg = sigma[i];
  const float inv2 = -0.5f / (sg * sg);
  const float c = rsqrtf(6.283185307179586f * sg);
  float4 g[4];
  float sum = 0.f;
#pragma unroll
  for (int r = 0; r < 4; ++r) {
    int j = r * 1024 + t * 4;
    float d0 = (float)(i - j);
    float d1 = (float)(i - j - 1);
    float d2 = (float)(i - j - 2);
    float d3 = (float)(i - j - 3);
    g[r].x = __expf(inv2 * d0 * d0) * c;
    g[r].y = __expf(inv2 * d1 * d1) * c;
    g[r].z = __expf(inv2 * d2 * d2) * c;
    g[r].w = __expf(inv2 * d3 * d3) * c;
    sum += g[r].x + g[r].y + g[r].z + g[r].w;
  }
  red[t] = sum;
  __syncthreads();
  for (int off = 128; off > 0; off >>= 1) {
    if (t < off) red[t] += red[t + off];
    __syncthreads();
  }
  const float inv = 1.0f / (red[0] + 1e-8f);
  float* Prow = P + (size_t)i * N_TOK;
#pragma unroll
  for (int r = 0; r < 4; ++r) {
    g[r].x *= inv; g[r].y *= inv; g[r].z *= inv; g[r].w *= inv;
    *(float4*)&Prow[r * 1024 + t * 4] = g[r];
  }
}

// ---------------------------------------------------------------------------
extern "C" void kernel_launch(void* const* d_in, const int* in_sizes, int n_in,
                              void* d_out, int out_size, void* d_ws,
                              size_t ws_size, hipStream_t stream) {
  const float* x = (const float*)d_in[0];
  const float* Wq = (const float*)d_in[1];
  const float* Wk = (const float*)d_in[2];
  const float* Wv = (const float*)d_in[3];
  const float* Ws = (const float*)d_in[4];

  float* out = (float*)d_out;
  float* Z = out;                        // [4096, 512]   fp32
  float* Pout = Z + (size_t)N_TOK * DM;  // [4096, 4096]  fp32 (written LAST)
  float* S = Pout + (size_t)N_TOK * N_TOK;

  // Stage Q/K/V inside the P slice of d_out (dead before tail writes P):
  const size_t E = (size_t)N_TOK * DM;   // 2M elements
  _Float16* Q16 = (_Float16*)Pout;       // [ 0, 4) MB
  _Float16* K16 = Q16 + E;               // [ 4, 8) MB
  _Float16* V16 = K16 + E;               // [ 8,12) MB
  _Float16* VT16 = V16 + E;              // [12,16) MB

  // ws (~280 MB): x16, Wc16, sigma, denom, fp16 partials, E16
  _Float16* x16 = (_Float16*)d_ws;            // 4 MB
  _Float16* Wc16 = x16 + E;                   // 1.5 MB [1536 x 512]
  float* sg = (float*)(Wc16 + 3 * DM * DM);   // 16 KB
  float* denom = sg + 4096;                   // 16 KB
  _Float16* Part16 = (_Float16*)(denom + 4096);  // 12 MB (3 x 2M fp16)
  _Float16* E16 = Part16 + 3 * E;             // 32 MB (exp scores, unnorm)

  const dim3 blk(256);

  // 1. pack x->fp16 + sigma + pack W->fp16 + zero denom (fused)
  pack_sigma<<<2817, blk, 0, stream>>>(x, Wq, Wk, Wv, Ws, x16, Wc16, sg, denom);

  // 2. fused QKV projection: [4096x1536] = x16 @ Wcat^T -> Q16,K16,V16 fp16
  mfma_f16<1><<<dim3(12, 32), blk, 0, stream>>>(
      x16, DM, Wc16, DM, DM, 1.0f, nullptr, 0, Q16, K16, V16, nullptr, nullptr);

  // 3. V -> V^T fp16
  transpose16<<<dim3(16, 128), blk, 0, stream>>>(V16, VT16);

  // 4. E16 = exp(Q@K^T / sqrt(D)) fp16 + row denominators (atomic)
  mfma_f16<4><<<dim3(32, 32), blk, 0, stream>>>(
      Q16, DM, K16, DM, DM, 1.0f / sqrtf((float)DM), nullptr, N_TOK, E16,
      nullptr, nullptr, nullptr, denom);

  // 5. Z = (E @ V) / denom, split-K x4 (z=0 -> Z fp32, z>0 -> fp16 partials)
  mfma_f16<2><<<dim3(4, 32, 4), blk, 0, stream>>>(
      E16, N_TOK, VT16, N_TOK, N_TOK / 4, 1.0f, Z, DM, nullptr, nullptr,
      nullptr, Part16, denom);

  // 6. fused tail: P rows + Z partial-reduce + S normalize
  tail_kernel<<<4096 + 2048 + 16384, blk, 0, stream>>>(sg, Pout, Z, Part16,
                                                       E16, denom, S);
}